// Round 3
// baseline (278.668 us; speedup 1.0000x reference)
//
#include <hip/hip_runtime.h>
#include <stdint.h>

#define NENT 16384
#define NREL 50
#define NE   262144

__device__ __forceinline__ float bf2f(uint32_t u){ return __uint_as_float(u << 16); }
// round-to-nearest-even f32 -> bf16, packed pair
__device__ __forceinline__ uint32_t fpack(float a, float b){
  uint32_t ua = __float_as_uint(a), ub = __float_as_uint(b);
  ua = (ua + 0x7fffu + ((ua >> 16) & 1u)) >> 16;
  ub = (ub + 0x7fffu + ((ub >> 16) & 1u)) >> 16;
  return ua | (ub << 16);
}

// ---- pass 1: destination-row degree count ----
__global__ void k_count(const int* __restrict__ eidx, int* __restrict__ deg){
  int e = blockIdx.x * 256 + threadIdx.x;
  atomicAdd(&deg[eidx[e]], 1);
}

// ---- pass 2: exclusive scan -> rowptr, deg_inv, and alpha*comps table ----
__global__ void k_scan(const int* __restrict__ deg, int* __restrict__ rowptr,
                       float* __restrict__ dinv,
                       const float* __restrict__ comps,
                       const float* __restrict__ alpha,
                       float* __restrict__ acomb){
  __shared__ int s[1024];
  int t = threadIdx.x;
  int base = t * 16;
  int sum = 0;
  #pragma unroll
  for (int j = 0; j < 16; ++j) sum += deg[base + j];
  s[t] = sum; __syncthreads();
  for (int off = 1; off < 1024; off <<= 1){
    int v = (t >= off) ? s[t - off] : 0;
    __syncthreads();
    s[t] += v;
    __syncthreads();
  }
  int run = s[t] - sum;   // exclusive prefix of this thread's chunk
  #pragma unroll
  for (int j = 0; j < 16; ++j){
    int d = deg[base + j];
    rowptr[base + j] = run;
    run += d;
    dinv[base + j] = (d > 0) ? rsqrtf((float)d) : 0.f;
  }
  if (t == 0) rowptr[NENT] = NE;
  if (t < NREL * 4){
    acomb[t] = alpha[t >> 2] * comps[t];
  }
}

// ---- pass 3: CSR fill ----
__global__ void k_fill(const int* __restrict__ eidx, const int* __restrict__ rowptr,
                       int* __restrict__ cursor, int* __restrict__ elist){
  int e = blockIdx.x * 256 + threadIdx.x;
  int row = eidx[e];
  int pos = atomicAdd(&cursor[row], 1);
  elist[rowptr[row] + pos] = e;
}

// ---- pass 4 (fused): per-block A_tile build in LDS + A_tile @ W GEMM ----
// Block: 256 threads (4 waves), 32 destination rows.
// A_tile: [row_local][kpair] uint (bf16 pair), k = b*128 + 2*lane(+1).
__global__ __launch_bounds__(256) void k_fused(
    const float* __restrict__ x,
    const int* __restrict__ eidx, const int* __restrict__ etype,
    const int* __restrict__ rowptr, const int* __restrict__ elist,
    const float* __restrict__ dinv, const float* __restrict__ acomb,
    const float* __restrict__ W, float* __restrict__ outf)
{
  __shared__ uint32_t A_lds[32 * 256];  // 32 KB (bf16 pairs)
  __shared__ float    Bs[64 * 128];     // 32 KB (one 64-k chunk of W, f32)

  int t = threadIdx.x;
  int lane = t & 63;
  int row0 = blockIdx.x * 32;
  const float2* xf2 = (const float2*)x;

  // ---- phase 1: one wave per row, 8 rows per wave ----
  for (int rr = (t >> 6); rr < 32; rr += 4){
    int i = row0 + rr;
    int s = rowptr[i], e = rowptr[i + 1];
    float di = dinv[i];
    float a0=0,a1=0,a2=0,a3=0,a4=0,a5=0,a6=0,a7=0;
    for (int j = s; j < e; ++j){
      int eid = elist[j];
      int col = eidx[NE + eid];
      int r   = etype[eid];
      float w = di * dinv[col];
      float4 ac = ((const float4*)acomb)[r];
      float2 h = xf2[col * 64 + lane];   // x[col][2*lane], x[col][2*lane+1]
      float m0 = w*ac.x, m1 = w*ac.y, m2 = w*ac.z, m3 = w*ac.w;
      a0 += m0*h.x; a1 += m0*h.y;
      a2 += m1*h.x; a3 += m1*h.y;
      a4 += m2*h.x; a5 += m2*h.y;
      a6 += m3*h.x; a7 += m3*h.y;
    }
    A_lds[rr*256 + lane]       = fpack(a0, a1);   // k = 0*128 + 2*lane
    A_lds[rr*256 + lane + 64]  = fpack(a2, a3);   // k = 1*128 + 2*lane
    A_lds[rr*256 + lane + 128] = fpack(a4, a5);   // k = 2*128 + 2*lane
    A_lds[rr*256 + lane + 192] = fpack(a6, a7);   // k = 3*128 + 2*lane
  }

  // ---- phase 2: out_tile[32,128] = A_tile[32,512] @ W[512,128] ----
  int tx = t & 31;              // cols tx*4 .. tx*4+3
  int ty = t >> 5;              // rows ty*4 .. ty*4+3  (8 groups x 4 = 32)
  float acc[16];
  #pragma unroll
  for (int i = 0; i < 16; ++i) acc[i] = 0.f;

  for (int k0 = 0; k0 < 512; k0 += 64){
    __syncthreads();            // phase-1 done (k0=0) / prev chunk consumed
    { // stage W chunk: straight 32 KB copy, f32
      const float4* B4 = (const float4*)(W + k0 * 128);
      float4* Bs4 = (float4*)Bs;
      #pragma unroll
      for (int j = 0; j < 8; ++j) Bs4[t + j * 256] = B4[t + j * 256];
    }
    __syncthreads();
    int kbase = k0 >> 1;
    #pragma unroll 4
    for (int m = 0; m < 16; ++m){         // 4 k-values per m
      float av[4][4];
      #pragma unroll
      for (int r = 0; r < 4; ++r){
        uint2 u2 = *(const uint2*)&A_lds[(ty*4 + r)*256 + kbase + 2*m];
        av[r][0] = bf2f(u2.x & 0xffffu); av[r][1] = bf2f(u2.x >> 16);
        av[r][2] = bf2f(u2.y & 0xffffu); av[r][3] = bf2f(u2.y >> 16);
      }
      #pragma unroll
      for (int kk = 0; kk < 4; ++kk){
        const float4 b = *(const float4*)&Bs[(4*m + kk)*128 + tx*4];
        #pragma unroll
        for (int r = 0; r < 4; ++r){
          acc[r*4+0] += av[r][kk]*b.x;
          acc[r*4+1] += av[r][kk]*b.y;
          acc[r*4+2] += av[r][kk]*b.z;
          acc[r*4+3] += av[r][kk]*b.w;
        }
      }
    }
  }

  #pragma unroll
  for (int r = 0; r < 4; ++r){
    int row = row0 + ty*4 + r;
    float4 o = make_float4(acc[r*4+0], acc[r*4+1], acc[r*4+2], acc[r*4+3]);
    *(float4*)&outf[row*128 + tx*4] = o;
  }
}

extern "C" void kernel_launch(void* const* d_in, const int* in_sizes, int n_in,
                              void* d_out, int out_size, void* d_ws, size_t ws_size,
                              hipStream_t stream){
  (void)in_sizes; (void)n_in; (void)out_size; (void)ws_size;
  const float* x     = (const float*)d_in[0];
  const float* bases = (const float*)d_in[1];
  const float* comps = (const float*)d_in[2];
  const float* alpha = (const float*)d_in[3];
  const int* eidx    = (const int*)d_in[4];
  const int* etype   = (const int*)d_in[5];

  // workspace layout (total 2 MB):
  char* ws = (char*)d_ws;
  int*   deg    = (int*)  (ws + 0);          //  64 KB
  int*   cursor = (int*)  (ws + (64 << 10)); //  64 KB
  float* dinv   = (float*)(ws + (128 << 10));//  64 KB
  int*   rowptr = (int*)  (ws + (192 << 10));//  64 KB + 4
  float* acomb  = (float*)(ws + (272 << 10));// 800 B (16B aligned)
  int*   elist  = (int*)  (ws + (1 << 20));  //   1 MB

  hipMemsetAsync(ws, 0, 128 << 10, stream);  // zero deg + cursor
  k_count<<<NE / 256, 256, 0, stream>>>(eidx, deg);
  k_scan <<<1, 1024, 0, stream>>>(deg, rowptr, dinv, comps, alpha, acomb);
  k_fill <<<NE / 256, 256, 0, stream>>>(eidx, rowptr, cursor, elist);
  k_fused<<<NENT / 32, 256, 0, stream>>>(x, eidx, etype, rowptr, elist, dinv,
                                         acomb, bases, (float*)d_out);
}

// Round 4
// 140.849 us; speedup vs baseline: 1.9785x; 1.9785x over previous
//
#include <hip/hip_runtime.h>
#include <stdint.h>

#define NENT 16384
#define NREL 50
#define NE   262144
#define BSTR 64      // bucket stride (max supported degree; Poisson(16) tail ~1e-19)

typedef __attribute__((ext_vector_type(8))) short short8;     // 8 bf16 = 4 VGPRs
typedef __attribute__((ext_vector_type(4))) float float4v;    // MFMA acc

__device__ __forceinline__ float bf2f(uint32_t u){ return __uint_as_float(u << 16); }
__device__ __forceinline__ uint32_t fpack(float a, float b){  // RNE f32->bf16 pair
  uint32_t ua = __float_as_uint(a), ub = __float_as_uint(b);
  ua = (ua + 0x7fffu + ((ua >> 16) & 1u)) >> 16;
  ub = (ub + 0x7fffu + ((ub >> 16) & 1u)) >> 16;
  return ua | (ub << 16);
}
__device__ __forceinline__ unsigned short f2bf(float a){
  uint32_t ua = __float_as_uint(a);
  return (unsigned short)((ua + 0x7fffu + ((ua >> 16) & 1u)) >> 16);
}
__device__ __forceinline__ float rdlane_f(float v, int j){
  return __uint_as_float((uint32_t)__builtin_amdgcn_readlane((int)__float_as_uint(v), j));
}

// ================= FAST PATH (needs ~21 MB ws) =================

// one pass: degree count + padded-bucket fill with packed (col | rel<<14)
__global__ void k_fill_bkt(const int* __restrict__ eidx, const int* __restrict__ etype,
                           int* __restrict__ deg, uint32_t* __restrict__ bucket){
  int e = blockIdx.x * 256 + threadIdx.x;
  int row = eidx[e], col = eidx[NE + e], r = etype[e];
  int pos = atomicAdd(&deg[row], 1);
  if (pos < BSTR) bucket[row * BSTR + pos] = (uint32_t)col | ((uint32_t)r << 14);
}

// dinv = rsqrt(deg), acomb = alpha*comps, W_T[n][k] = bf16(W[k][n])
__global__ void k_prep(const int* __restrict__ deg, float* __restrict__ dinv,
                       const float* __restrict__ alpha, const float* __restrict__ comps,
                       float* __restrict__ acomb,
                       const float* __restrict__ W, unsigned short* __restrict__ WT){
  int gid = blockIdx.x * 256 + threadIdx.x;          // 65536 threads
  if (gid < NENT){
    int d = deg[gid];
    dinv[gid] = (d > 0) ? rsqrtf((float)d) : 0.f;
  }
  if (gid < NREL * 4) acomb[gid] = alpha[gid >> 2] * comps[gid];
  int n = gid >> 9, k = gid & 511;                   // WT[n*512+k] = W[k*128+n]
  WT[gid] = f2bf(W[k * 128 + n]);
}

// one wave per destination row; zero LDS; A row -> bf16 pairs
__global__ __launch_bounds__(256) void k_agg(
    const float* __restrict__ x, const int* __restrict__ deg,
    const float* __restrict__ dinv, const float* __restrict__ acomb,
    const uint32_t* __restrict__ bucket, uint32_t* __restrict__ Au){
  int lane = threadIdx.x & 63;
  int i = (blockIdx.x * 256 + threadIdx.x) >> 6;     // row = global wave id
  int o = i * 256 + lane;
  int d = deg[i];
  if (d == 0){ Au[o] = 0; Au[o+64] = 0; Au[o+128] = 0; Au[o+192] = 0; return; }
  int de = min(d, BSTR);
  float di = rsqrtf((float)d);
  // cooperative prefetch: lane j holds record j (lanes >= de replicate last)
  uint32_t rec = bucket[i * BSTR + min(lane, de - 1)];
  int  colL = (int)(rec & 0x3FFFu);
  int  rL   = (int)(rec >> 14);
  float wL  = di * dinv[colL];
  float4 ac = ((const float4*)acomb)[rL];
  float w0 = wL * ac.x, w1 = wL * ac.y, w2 = wL * ac.z, w3 = wL * ac.w;
  const float2* xf2 = (const float2*)x;
  float a0=0,a1=0,a2=0,a3=0,a4=0,a5=0,a6=0,a7=0;
  for (int j = 0; j < de; ++j){
    int   cj = __builtin_amdgcn_readlane(colL, j);
    float m0 = rdlane_f(w0, j), m1 = rdlane_f(w1, j);
    float m2 = rdlane_f(w2, j), m3 = rdlane_f(w3, j);
    float2 h = xf2[cj * 64 + lane];                  // x[col][2*lane(+1)]
    a0 += m0*h.x; a1 += m0*h.y;
    a2 += m1*h.x; a3 += m1*h.y;
    a4 += m2*h.x; a5 += m2*h.y;
    a6 += m3*h.x; a7 += m3*h.y;
  }
  Au[o]       = fpack(a0, a1);   // A[i][b*128 + 2*lane], b=0
  Au[o + 64]  = fpack(a2, a3);   // b=1
  Au[o + 128] = fpack(a4, a5);   // b=2
  Au[o + 192] = fpack(a6, a7);   // b=3
}

// out[16384,128] = A[16384,512]bf16 @ W[512,128]bf16 via mfma_16x16x32_bf16.
// Wave: 16 rows x 128 cols (1 A-frag, 8 B-frags per k-step). No LDS.
__global__ __launch_bounds__(256) void k_gemm(
    const uint32_t* __restrict__ Au, const unsigned short* __restrict__ WT,
    float* __restrict__ outf){
  int lane = threadIdx.x & 63;
  int wv   = threadIdx.x >> 6;
  int m16  = lane & 15;
  int quad = lane >> 4;
  int mbase = blockIdx.x * 64 + wv * 16;
  const short8* Arow = (const short8*)(Au + (mbase + m16) * 256);  // 64 x short8
  float4v acc[8];
  #pragma unroll
  for (int n = 0; n < 8; ++n) acc[n] = (float4v){0.f,0.f,0.f,0.f};

  #pragma unroll 4
  for (int k0 = 0; k0 < 512; k0 += 32){
    short8 aF = Arow[(k0 >> 3) + quad];              // A[m][k0+quad*8 ..+7]
    #pragma unroll
    for (int n = 0; n < 8; ++n){
      const short8* Bcol = (const short8*)(WT + (n * 16 + m16) * 512);
      short8 bF = Bcol[(k0 >> 3) + quad];            // B[k0+quad*8..+7][n]
      acc[n] = __builtin_amdgcn_mfma_f32_16x16x32_bf16(aF, bF, acc[n], 0, 0, 0);
    }
  }
  int mrow = mbase + quad * 4;                        // C/D: row=quad*4+reg, col=lane&15
  #pragma unroll
  for (int n = 0; n < 8; ++n){
    int c = n * 16 + m16;
    #pragma unroll
    for (int r = 0; r < 4; ++r) outf[(mrow + r) * 128 + c] = acc[n][r];
  }
}

// ================= FALLBACK PATH (round-3, proven, 2 MB ws) =================

__global__ void k_count(const int* __restrict__ eidx, int* __restrict__ deg){
  int e = blockIdx.x * 256 + threadIdx.x;
  atomicAdd(&deg[eidx[e]], 1);
}

__global__ void k_scan(const int* __restrict__ deg, int* __restrict__ rowptr,
                       float* __restrict__ dinv,
                       const float* __restrict__ comps,
                       const float* __restrict__ alpha,
                       float* __restrict__ acomb){
  __shared__ int s[1024];
  int t = threadIdx.x;
  int base = t * 16;
  int sum = 0;
  #pragma unroll
  for (int j = 0; j < 16; ++j) sum += deg[base + j];
  s[t] = sum; __syncthreads();
  for (int off = 1; off < 1024; off <<= 1){
    int v = (t >= off) ? s[t - off] : 0;
    __syncthreads();
    s[t] += v;
    __syncthreads();
  }
  int run = s[t] - sum;
  #pragma unroll
  for (int j = 0; j < 16; ++j){
    int d = deg[base + j];
    rowptr[base + j] = run;
    run += d;
    dinv[base + j] = (d > 0) ? rsqrtf((float)d) : 0.f;
  }
  if (t == 0) rowptr[NENT] = NE;
  if (t < NREL * 4) acomb[t] = alpha[t >> 2] * comps[t];
}

__global__ void k_fill(const int* __restrict__ eidx, const int* __restrict__ rowptr,
                       int* __restrict__ cursor, int* __restrict__ elist){
  int e = blockIdx.x * 256 + threadIdx.x;
  int row = eidx[e];
  int pos = atomicAdd(&cursor[row], 1);
  elist[rowptr[row] + pos] = e;
}

__global__ __launch_bounds__(256) void k_fused(
    const float* __restrict__ x,
    const int* __restrict__ eidx, const int* __restrict__ etype,
    const int* __restrict__ rowptr, const int* __restrict__ elist,
    const float* __restrict__ dinv, const float* __restrict__ acomb,
    const float* __restrict__ W, float* __restrict__ outf)
{
  __shared__ uint32_t A_lds[32 * 256];
  __shared__ float    Bs[64 * 128];
  int t = threadIdx.x;
  int lane = t & 63;
  int row0 = blockIdx.x * 32;
  const float2* xf2 = (const float2*)x;
  for (int rr = (t >> 6); rr < 32; rr += 4){
    int i = row0 + rr;
    int s = rowptr[i], e = rowptr[i + 1];
    float di = dinv[i];
    float a0=0,a1=0,a2=0,a3=0,a4=0,a5=0,a6=0,a7=0;
    for (int j = s; j < e; ++j){
      int eid = elist[j];
      int col = eidx[NE + eid];
      int r   = etype[eid];
      float w = di * dinv[col];
      float4 ac = ((const float4*)acomb)[r];
      float2 h = xf2[col * 64 + lane];
      float m0 = w*ac.x, m1 = w*ac.y, m2 = w*ac.z, m3 = w*ac.w;
      a0 += m0*h.x; a1 += m0*h.y;
      a2 += m1*h.x; a3 += m1*h.y;
      a4 += m2*h.x; a5 += m2*h.y;
      a6 += m3*h.x; a7 += m3*h.y;
    }
    A_lds[rr*256 + lane]       = fpack(a0, a1);
    A_lds[rr*256 + lane + 64]  = fpack(a2, a3);
    A_lds[rr*256 + lane + 128] = fpack(a4, a5);
    A_lds[rr*256 + lane + 192] = fpack(a6, a7);
  }
  int tx = t & 31;
  int ty = t >> 5;
  float acc[16];
  #pragma unroll
  for (int i = 0; i < 16; ++i) acc[i] = 0.f;
  for (int k0 = 0; k0 < 512; k0 += 64){
    __syncthreads();
    {
      const float4* B4 = (const float4*)(W + k0 * 128);
      float4* Bs4 = (float4*)Bs;
      #pragma unroll
      for (int j = 0; j < 8; ++j) Bs4[t + j * 256] = B4[t + j * 256];
    }
    __syncthreads();
    int kbase = k0 >> 1;
    #pragma unroll 4
    for (int m = 0; m < 16; ++m){
      float av[4][4];
      #pragma unroll
      for (int r = 0; r < 4; ++r){
        uint2 u2 = *(const uint2*)&A_lds[(ty*4 + r)*256 + kbase + 2*m];
        av[r][0] = bf2f(u2.x & 0xffffu); av[r][1] = bf2f(u2.x >> 16);
        av[r][2] = bf2f(u2.y & 0xffffu); av[r][3] = bf2f(u2.y >> 16);
      }
      #pragma unroll
      for (int kk = 0; kk < 4; ++kk){
        const float4 b = *(const float4*)&Bs[(4*m + kk)*128 + tx*4];
        #pragma unroll
        for (int r = 0; r < 4; ++r){
          acc[r*4+0] += av[r][kk]*b.x;
          acc[r*4+1] += av[r][kk]*b.y;
          acc[r*4+2] += av[r][kk]*b.z;
          acc[r*4+3] += av[r][kk]*b.w;
        }
      }
    }
  }
  #pragma unroll
  for (int r = 0; r < 4; ++r){
    int row = row0 + ty*4 + r;
    float4 o = make_float4(acc[r*4+0], acc[r*4+1], acc[r*4+2], acc[r*4+3]);
    *(float4*)&outf[row*128 + tx*4] = o;
  }
}

// ================= launch =================

extern "C" void kernel_launch(void* const* d_in, const int* in_sizes, int n_in,
                              void* d_out, int out_size, void* d_ws, size_t ws_size,
                              hipStream_t stream){
  (void)in_sizes; (void)n_in; (void)out_size;
  const float* x     = (const float*)d_in[0];
  const float* bases = (const float*)d_in[1];
  const float* comps = (const float*)d_in[2];
  const float* alpha = (const float*)d_in[3];
  const int* eidx    = (const int*)d_in[4];
  const int* etype   = (const int*)d_in[5];
  char* ws = (char*)d_ws;

  const size_t FAST_WS = (size_t)(5u << 20) + (size_t)NENT * 512 * 2;  // ~21 MB
  if (ws_size >= FAST_WS){
    int*      deg    = (int*)      (ws + 0);            //  64 KB
    float*    dinv   = (float*)    (ws + (64  << 10));  //  64 KB
    float*    acomb  = (float*)    (ws + (128 << 10));  //  800 B
    unsigned short* WT = (unsigned short*)(ws + (192 << 10)); // 128 KB
    uint32_t* bucket = (uint32_t*) (ws + (512 << 10));  //   4 MB
    uint32_t* Au     = (uint32_t*) (ws + (5u  << 20));  //  16 MB

    hipMemsetAsync(deg, 0, 64 << 10, stream);
    k_fill_bkt<<<NE / 256, 256, 0, stream>>>(eidx, etype, deg, bucket);
    k_prep    <<<256, 256, 0, stream>>>(deg, dinv, alpha, comps, acomb, bases, WT);
    k_agg     <<<NENT / 4, 256, 0, stream>>>(x, deg, dinv, acomb, bucket, Au);
    k_gemm    <<<NENT / 64, 256, 0, stream>>>(Au, WT, (float*)d_out);
  } else {
    int*   deg    = (int*)  (ws + 0);
    int*   cursor = (int*)  (ws + (64 << 10));
    float* dinv   = (float*)(ws + (128 << 10));
    int*   rowptr = (int*)  (ws + (192 << 10));
    float* acomb  = (float*)(ws + (272 << 10));
    int*   elist  = (int*)  (ws + (1 << 20));

    hipMemsetAsync(ws, 0, 128 << 10, stream);
    k_count<<<NE / 256, 256, 0, stream>>>(eidx, deg);
    k_scan <<<1, 1024, 0, stream>>>(deg, rowptr, dinv, comps, alpha, acomb);
    k_fill <<<NE / 256, 256, 0, stream>>>(eidx, rowptr, cursor, elist);
    k_fused<<<NENT / 32, 256, 0, stream>>>(x, eidx, etype, rowptr, elist, dinv,
                                           acomb, bases, (float*)d_out);
  }
}

// Round 5
// 126.963 us; speedup vs baseline: 2.1949x; 1.1094x over previous
//
#include <hip/hip_runtime.h>
#include <stdint.h>

#define NENT 16384
#define NREL 50
#define NE   262144
#define BSTR 64      // bucket stride (max supported degree; Poisson(16) tail ~1e-19)

typedef __attribute__((ext_vector_type(8))) short short8;     // 8 bf16 = 4 VGPRs
typedef __attribute__((ext_vector_type(4))) float float4v;    // MFMA acc

__device__ __forceinline__ uint32_t fpack(float a, float b){  // RNE f32->bf16 pair
  uint32_t ua = __float_as_uint(a), ub = __float_as_uint(b);
  ua = (ua + 0x7fffu + ((ua >> 16) & 1u)) >> 16;
  ub = (ub + 0x7fffu + ((ub >> 16) & 1u)) >> 16;
  return ua | (ub << 16);
}
__device__ __forceinline__ unsigned short f2bf(float a){
  uint32_t ua = __float_as_uint(a);
  return (unsigned short)((ua + 0x7fffu + ((ua >> 16) & 1u)) >> 16);
}
__device__ __forceinline__ float rdlane_f(float v, int j){
  return __uint_as_float((uint32_t)__builtin_amdgcn_readlane((int)__float_as_uint(v), j));
}

// ---- pass 0: zero deg + acomb table + W transpose to bf16 ----
// 65536 threads. WT[n*512+k] = bf16(W[k*128+n])  (B-operand layout for MFMA).
__global__ void k_prep0(int* __restrict__ deg,
                        const float* __restrict__ alpha, const float* __restrict__ comps,
                        float* __restrict__ acomb,
                        const float* __restrict__ W, unsigned short* __restrict__ WT){
  int gid = blockIdx.x * 256 + threadIdx.x;
  if (gid < NENT) deg[gid] = 0;
  if (gid < NREL * 4) acomb[gid] = alpha[gid >> 2] * comps[gid];
  int n = gid >> 9, k = gid & 511;
  WT[gid] = f2bf(W[k * 128 + n]);
}

// ---- pass 1: degree count + padded-bucket fill, packed (col | rel<<14) ----
__global__ void k_fill_bkt(const int* __restrict__ eidx, const int* __restrict__ etype,
                           int* __restrict__ deg, uint32_t* __restrict__ bucket){
  int e = blockIdx.x * 256 + threadIdx.x;
  int row = eidx[e], col = eidx[NE + e], r = etype[e];
  int pos = atomicAdd(&deg[row], 1);
  if (pos < BSTR) bucket[row * BSTR + pos] = (uint32_t)col | ((uint32_t)r << 14);
}

// ---- pass 2: one wave per destination row; ILP-4 gather; A row -> bf16 pairs ----
__global__ __launch_bounds__(256) void k_agg(
    const float* __restrict__ x, const int* __restrict__ deg,
    const float* __restrict__ acomb, const uint32_t* __restrict__ bucket,
    uint32_t* __restrict__ Au){
  int lane = threadIdx.x & 63;
  int i = (blockIdx.x * 256 + threadIdx.x) >> 6;     // row = global wave id
  int o = i * 256 + lane;
  int d = deg[i];
  if (d == 0){ Au[o] = 0; Au[o+64] = 0; Au[o+128] = 0; Au[o+192] = 0; return; }
  int de = min(d, BSTR);
  float di = rsqrtf((float)d);
  // cooperative prefetch: lane j holds record j; pad lanes carry weight 0
  uint32_t rec = bucket[i * BSTR + min(lane, de - 1)];
  int  colL = (int)(rec & 0x3FFFu);
  int  rL   = (int)(rec >> 14);
  int  dc   = deg[colL];
  float wL  = (lane < de && dc > 0) ? di * rsqrtf((float)dc) : 0.f;
  float4 ac = ((const float4*)acomb)[rL];
  float w0 = wL * ac.x, w1 = wL * ac.y, w2 = wL * ac.z, w3 = wL * ac.w;
  const float2* xf2 = (const float2*)x;
  float a0=0,a1=0,a2=0,a3=0,a4=0,a5=0,a6=0,a7=0;
  int rde = (de + 3) & ~3;                           // padded lanes contribute 0
  for (int j = 0; j < rde; j += 4){
    #pragma unroll
    for (int jj = 0; jj < 4; ++jj){
      int   cj = __builtin_amdgcn_readlane(colL, j + jj);
      float m0 = rdlane_f(w0, j + jj), m1 = rdlane_f(w1, j + jj);
      float m2 = rdlane_f(w2, j + jj), m3 = rdlane_f(w3, j + jj);
      float2 h = xf2[cj * 64 + lane];                // x[col][2*lane(+1)]
      a0 += m0*h.x; a1 += m0*h.y;
      a2 += m1*h.x; a3 += m1*h.y;
      a4 += m2*h.x; a5 += m2*h.y;
      a6 += m3*h.x; a7 += m3*h.y;
    }
  }
  Au[o]       = fpack(a0, a1);   // A[i][b*128 + 2*lane], b=0
  Au[o + 64]  = fpack(a2, a3);   // b=1
  Au[o + 128] = fpack(a4, a5);   // b=2
  Au[o + 192] = fpack(a6, a7);   // b=3
}

// ---- pass 3: out[16384,128] = A[16384,512]bf16 @ W[512,128]bf16, MFMA ----
// 1024 blocks x 256 thr: block = 16 rows; wave wv covers cols wv*32..wv*32+31.
__global__ __launch_bounds__(256) void k_gemm(
    const uint32_t* __restrict__ Au, const unsigned short* __restrict__ WT,
    float* __restrict__ outf){
  int lane = threadIdx.x & 63;
  int wv   = threadIdx.x >> 6;
  int m16  = lane & 15;
  int quad = lane >> 4;
  int m0   = blockIdx.x * 16;
  const short8* Arow = (const short8*)(Au + (m0 + m16) * 256);
  int c0 = (wv * 2) * 16 + m16, c1 = (wv * 2 + 1) * 16 + m16;
  const short8* B0 = (const short8*)(WT + c0 * 512);
  const short8* B1 = (const short8*)(WT + c1 * 512);
  float4v acc0 = {0.f,0.f,0.f,0.f}, acc1 = {0.f,0.f,0.f,0.f};
  #pragma unroll
  for (int k0 = 0; k0 < 512; k0 += 32){
    int idx = (k0 >> 3) + quad;
    short8 aF = Arow[idx];                           // A[m][k0+quad*8 ..+7]
    acc0 = __builtin_amdgcn_mfma_f32_16x16x32_bf16(aF, B0[idx], acc0, 0, 0, 0);
    acc1 = __builtin_amdgcn_mfma_f32_16x16x32_bf16(aF, B1[idx], acc1, 0, 0, 0);
  }
  int mrow = m0 + quad * 4;                          // C/D: row=quad*4+reg, col=lane&15
  #pragma unroll
  for (int r = 0; r < 4; ++r){
    outf[(mrow + r) * 128 + c0] = acc0[r];
    outf[(mrow + r) * 128 + c1] = acc1[r];
  }
}

extern "C" void kernel_launch(void* const* d_in, const int* in_sizes, int n_in,
                              void* d_out, int out_size, void* d_ws, size_t ws_size,
                              hipStream_t stream){
  (void)in_sizes; (void)n_in; (void)out_size; (void)ws_size;
  const float* x     = (const float*)d_in[0];
  const float* bases = (const float*)d_in[1];
  const float* comps = (const float*)d_in[2];
  const float* alpha = (const float*)d_in[3];
  const int* eidx    = (const int*)d_in[4];
  const int* etype   = (const int*)d_in[5];
  char* ws = (char*)d_ws;

  // workspace (~21 MB; ws_size measured ~268 MB via harness poison traffic)
  int*      deg    = (int*)      (ws + 0);            //  64 KB
  float*    acomb  = (float*)    (ws + (64  << 10));  //  800 B
  unsigned short* WT = (unsigned short*)(ws + (128 << 10)); // 128 KB
  uint32_t* bucket = (uint32_t*) (ws + (512 << 10));  //   4 MB
  uint32_t* Au     = (uint32_t*) (ws + (5u  << 20));  //  16 MB

  k_prep0   <<<256, 256, 0, stream>>>(deg, alpha, comps, acomb, bases, WT);
  k_fill_bkt<<<NE / 256, 256, 0, stream>>>(eidx, etype, deg, bucket);
  k_agg     <<<NENT / 4, 256, 0, stream>>>(x, deg, acomb, bucket, Au);
  k_gemm    <<<NENT / 16, 256, 0, stream>>>(Au, WT, (float*)d_out);
}

// Round 6
// 119.724 us; speedup vs baseline: 2.3276x; 1.0605x over previous
//
#include <hip/hip_runtime.h>
#include <stdint.h>

#define NENT 16384
#define NREL 50
#define NE   262144
#define BSTR 64      // bucket stride (max supported degree; Binomial(262144,1/16384) tail ~0)
#define ASTR 260     // LDS A-tile row stride in uints (256 + 4 pad -> bank shift 4)

typedef __attribute__((ext_vector_type(8))) short short8;     // 8 bf16 = 4 VGPRs
typedef __attribute__((ext_vector_type(4))) float float4v;    // MFMA acc

__device__ __forceinline__ float bf2f(uint32_t u){ return __uint_as_float(u << 16); }
__device__ __forceinline__ uint32_t fpack(float a, float b){  // RNE f32->bf16 pair
  uint32_t ua = __float_as_uint(a), ub = __float_as_uint(b);
  ua = (ua + 0x7fffu + ((ua >> 16) & 1u)) >> 16;
  ub = (ub + 0x7fffu + ((ub >> 16) & 1u)) >> 16;
  return ua | (ub << 16);
}
__device__ __forceinline__ unsigned short f2bf(float a){
  uint32_t ua = __float_as_uint(a);
  return (unsigned short)((ua + 0x7fffu + ((ua >> 16) & 1u)) >> 16);
}
__device__ __forceinline__ float rdlane_f(float v, int j){
  return __uint_as_float((uint32_t)__builtin_amdgcn_readlane((int)__float_as_uint(v), j));
}

// ---- pass 0: zero deg + acomb + WT (bf16 W^T) + xbf (bf16 x) ----
// 256 blocks x 256 thr = 65536 threads.
__global__ void k_prep0(int* __restrict__ deg,
                        const float* __restrict__ alpha, const float* __restrict__ comps,
                        float* __restrict__ acomb,
                        const float* __restrict__ W, unsigned short* __restrict__ WT,
                        const float* __restrict__ x, uint32_t* __restrict__ xbf){
  int gid = blockIdx.x * 256 + threadIdx.x;
  if (gid < NENT) deg[gid] = 0;
  if (gid < NREL * 4) acomb[gid] = alpha[gid >> 2] * comps[gid];
  { // WT[n*512+k] = bf16(W[k*128+n])
    int n = gid >> 9, k = gid & 511;
    WT[gid] = f2bf(W[k * 128 + n]);
  }
  { // xbf: 2M f32 -> 1M uint pairs; 32 f32 per thread
    const float4* xin = (const float4*)(x + gid * 32);
    uint32_t* xo = xbf + gid * 16;
    #pragma unroll
    for (int j = 0; j < 8; ++j){
      float4 p = xin[j];
      xo[j * 2]     = fpack(p.x, p.y);
      xo[j * 2 + 1] = fpack(p.z, p.w);
    }
  }
}

// ---- pass 1: degree count + padded-bucket fill, packed (col | rel<<14) ----
__global__ void k_fill_bkt(const int* __restrict__ eidx, const int* __restrict__ etype,
                           int* __restrict__ deg, uint32_t* __restrict__ bucket){
  int e = blockIdx.x * 256 + threadIdx.x;
  int row = eidx[e], col = eidx[NE + e], r = etype[e];
  int pos = atomicAdd(&deg[row], 1);
  if (pos < BSTR) bucket[row * BSTR + pos] = (uint32_t)col | ((uint32_t)r << 14);
}

// ---- pass 2 (fused): block = 16 rows. Phase 1: aggregate A-tile (bf16) into LDS.
//      Phase 2: out_tile[16,128] = A[16,512] @ W[512,128] via mfma_16x16x32_bf16.
__global__ __launch_bounds__(256) void k_fused(
    const uint32_t* __restrict__ xbf, const int* __restrict__ deg,
    const float* __restrict__ acomb, const uint32_t* __restrict__ bucket,
    const unsigned short* __restrict__ WT, float* __restrict__ outf)
{
  __shared__ uint32_t A_lds[16 * ASTR];   // 16.6 KB, row stride 260 uints
  int t = threadIdx.x, lane = t & 63, wv = t >> 6;
  int row0 = blockIdx.x * 16;

  // ---- phase 1: wave wv aggregates rows wv*4 .. wv*4+3 ----
  for (int rr = wv * 4; rr < wv * 4 + 4; ++rr){
    int i = row0 + rr;
    int d = deg[i];
    uint32_t* Arow = &A_lds[rr * ASTR];
    if (d == 0){
      Arow[lane] = 0; Arow[lane+64] = 0; Arow[lane+128] = 0; Arow[lane+192] = 0;
      continue;
    }
    int de = min(d, BSTR);
    float di = rsqrtf((float)d);
    uint32_t rec = bucket[i * BSTR + min(lane, de - 1)];
    int colL = (int)(rec & 0x3FFFu);
    int rL   = (int)(rec >> 14);
    int dc   = deg[colL];
    float wL = (lane < de && dc > 0) ? di * rsqrtf((float)dc) : 0.f;
    float4 ac = ((const float4*)acomb)[rL];
    float w0 = wL*ac.x, w1 = wL*ac.y, w2 = wL*ac.z, w3 = wL*ac.w;
    float a0=0,a1=0,a2=0,a3=0,a4=0,a5=0,a6=0,a7=0;
    int rde = (de + 3) & ~3;               // pad lanes carry weight 0
    for (int j = 0; j < rde; j += 4){
      #pragma unroll
      for (int jj = 0; jj < 4; ++jj){
        int   cj = __builtin_amdgcn_readlane(colL, j + jj);
        float m0 = rdlane_f(w0, j + jj), m1 = rdlane_f(w1, j + jj);
        float m2 = rdlane_f(w2, j + jj), m3 = rdlane_f(w3, j + jj);
        uint32_t hv = xbf[cj * 64 + lane];           // x[col][2*lane(+1)] bf16 pair
        float h0 = bf2f(hv & 0xffffu), h1 = bf2f(hv >> 16);
        a0 += m0*h0; a1 += m0*h1;
        a2 += m1*h0; a3 += m1*h1;
        a4 += m2*h0; a5 += m2*h1;
        a6 += m3*h0; a7 += m3*h1;
      }
    }
    Arow[lane]       = fpack(a0, a1);      // A[rr][b*128 + 2*lane], b=0
    Arow[lane + 64]  = fpack(a2, a3);      // b=1
    Arow[lane + 128] = fpack(a4, a5);      // b=2
    Arow[lane + 192] = fpack(a6, a7);      // b=3
  }
  __syncthreads();

  // ---- phase 2: MFMA. Wave wv covers cols (wv*2)*16 and (wv*2+1)*16 blocks ----
  int m16 = lane & 15, quad = lane >> 4;
  int c0 = (wv * 2) * 16 + m16, c1 = c0 + 16;
  const short8* B0 = (const short8*)(WT + c0 * 512);
  const short8* B1 = (const short8*)(WT + c1 * 512);
  const uint32_t* Abase = &A_lds[m16 * ASTR];
  float4v acc0 = {0.f,0.f,0.f,0.f}, acc1 = {0.f,0.f,0.f,0.f};
  #pragma unroll
  for (int k0 = 0; k0 < 512; k0 += 32){
    short8 aF = *(const short8*)&Abase[(k0 >> 1) + quad * 4];  // A[m16][k0+quad*8..+7]
    int idx = (k0 >> 3) + quad;
    acc0 = __builtin_amdgcn_mfma_f32_16x16x32_bf16(aF, B0[idx], acc0, 0, 0, 0);
    acc1 = __builtin_amdgcn_mfma_f32_16x16x32_bf16(aF, B1[idx], acc1, 0, 0, 0);
  }
  int mrow = row0 + quad * 4;              // C/D: row = quad*4 + reg, col = lane&15
  #pragma unroll
  for (int r = 0; r < 4; ++r){
    outf[(mrow + r) * 128 + c0] = acc0[r];
    outf[(mrow + r) * 128 + c1] = acc1[r];
  }
}

extern "C" void kernel_launch(void* const* d_in, const int* in_sizes, int n_in,
                              void* d_out, int out_size, void* d_ws, size_t ws_size,
                              hipStream_t stream){
  (void)in_sizes; (void)n_in; (void)out_size; (void)ws_size;
  const float* x     = (const float*)d_in[0];
  const float* bases = (const float*)d_in[1];
  const float* comps = (const float*)d_in[2];
  const float* alpha = (const float*)d_in[3];
  const int* eidx    = (const int*)d_in[4];
  const int* etype   = (const int*)d_in[5];
  char* ws = (char*)d_ws;

  // workspace (~9.5 MB; ws_size ~268 MB per harness poison traffic)
  int*      deg    = (int*)      (ws + 0);            //  64 KB
  float*    acomb  = (float*)    (ws + (64  << 10));  //  800 B
  unsigned short* WT = (unsigned short*)(ws + (128 << 10)); // 128 KB
  uint32_t* xbf    = (uint32_t*) (ws + (512 << 10));  //   4 MB (bf16 x)
  uint32_t* bucket = (uint32_t*) (ws + (5u  << 20));  //   4 MB

  k_prep0   <<<256, 256, 0, stream>>>(deg, alpha, comps, acomb, bases, WT, x, xbf);
  k_fill_bkt<<<NE / 256, 256, 0, stream>>>(eidx, etype, deg, bucket);
  k_fused   <<<NENT / 16, 256, 0, stream>>>(xbf, deg, acomb, bucket, WT, (float*)d_out);
}